// Round 1
// baseline (1127.811 us; speedup 1.0000x reference)
//
#include <hip/hip_runtime.h>
#include <math.h>

#define FDIM 76
#define NA 3
#define NCH 85
#define NCLS 80
#define KLAB 40
#define NB 16
#define CIN 256
// label record: 16 floats
// 0 ttlx 1 ttly 2 tbrx 3 tbry 4 area 5 valid 6 tvx 7 tvy 8 tlw 9 tlh 10 cls 11 scale 12 assign 13 best_n 14 ti 15 tj

__device__ __forceinline__ float sigm(float x) { return 1.0f / (1.0f + expf(-x)); }
__device__ __forceinline__ float bce_full(float p, float t) {
    return -(t * fmaxf(logf(p), -100.0f) + (1.0f - t) * fmaxf(logf(1.0f - p), -100.0f));
}
__device__ __forceinline__ float bce1(float p) { return -fmaxf(logf(p), -100.0f); }
__device__ __forceinline__ float bce0(float p) { return -fmaxf(logf(1.0f - p), -100.0f); }

__global__ __launch_bounds__(64) void yolo_lab(const float* __restrict__ labels,
                                               float* __restrict__ lrec) {
    int idx = blockIdx.x * 64 + threadIdx.x;
    if (idx >= NB * KLAB) return;
    const float* l = labels + idx * 5;
    float cls = l[0], x = l[1], y = l[2], ww = l[3], hh = l[4];
    bool valid = (cls + x + y + ww + hh) > 0.0f;
    float tx = x * FDIM, ty = y * FDIM, tw = ww * FDIM, th = hh * FDIM;
    int ti = (int)tx, tj = (int)ty;
    float area_a = (tw - tx) * (th - ty);   // replicate reference's corner-style area here
    const float aw[9] = {1.25f, 2.0f, 4.125f, 3.75f, 7.75f, 7.375f, 14.5f, 19.5f, 46.625f};
    const float ah[9] = {1.625f, 3.75f, 2.875f, 7.625f, 5.625f, 14.875f, 11.25f, 24.75f, 40.75f};
    float best = -1e30f;
    int bi = 0;
    for (int n = 0; n < 9; n++) {
        float bw = fminf(tw, aw[n]), bh = fminf(th, ah[n]);
        float ai = ((tx < bw) && (ty < bh)) ? (bw - tx) * (bh - ty) : 0.0f;
        float iou = valid ? ai / (area_a + aw[n] * ah[n] - ai) : -1.0f;
        if (iou > best) { best = iou; bi = n; }   // first-max wins == jnp.argmax
    }
    int bn = bi % 3;
    bool assign = valid && (bi < 3);
    float* r = lrec + idx * 16;
    r[0] = tx - 0.5f * tw; r[1] = ty - 0.5f * th;
    r[2] = tx + 0.5f * tw; r[3] = ty + 0.5f * th;
    r[4] = tw * th; r[5] = valid ? 1.0f : 0.0f;
    r[6] = tx - (float)ti; r[7] = ty - (float)tj;
    r[8] = logf(tw / aw[bn] + 1e-16f); r[9] = logf(th / ah[bn] + 1e-16f);
    r[10] = cls; r[11] = sqrtf(2.0f - tw * th / (float)(FDIM * FDIM));
    r[12] = assign ? 1.0f : 0.0f; r[13] = (float)bn; r[14] = (float)ti; r[15] = (float)tj;
}

__global__ __launch_bounds__(256) void yolo_main(const float* __restrict__ xin,
                                                 const float* __restrict__ Wm,
                                                 const float* __restrict__ bias,
                                                 const float* __restrict__ lrec,
                                                 float* __restrict__ accum) {
    const int blk = blockIdx.x;          // 0..NB*FDIM-1
    const int b = blk / FDIM;
    const int h = blk - b * FDIM;
    const int t = threadIdx.x;

    __shared__ float Xs[64][FDIM];       // one K-chunk of xin[b, kc*64..+63, h, :]
    __shared__ float Lb[KLAB * 16];
    __shared__ float red[4][8];

    for (int i = t; i < KLAB * 16; i += 256) Lb[i] = lrec[b * KLAB * 16 + i];

    const int a = t / FDIM;              // anchor (valid when t < 228)
    const int w = t - a * FDIM;

    float acc[NCH];
#pragma unroll
    for (int i = 0; i < NCH; i++) acc[i] = 0.0f;

    const float* xb = xin + ((size_t)(b * CIN) * FDIM + h) * FDIM;
    const int wbase = a * NCH * CIN;

    for (int kc = 0; kc < 4; ++kc) {
        __syncthreads();
        // stage 64 channel-rows, fully coalesced (4864 = 19*256)
        for (int i = t; i < 64 * FDIM; i += 256) {
            int cc = i / FDIM;
            int wwi = i - cc * FDIM;
            Xs[cc][wwi] = xb[(size_t)(kc * 64 + cc) * (FDIM * FDIM) + wwi];
        }
        __syncthreads();
        if (t < 228) {
#pragma unroll
            for (int chb = 0; chb < 5; ++chb) {   // 5 passes x 17 rows = 85 channels
                const float* wp = Wm + wbase + (chb * 17) * CIN + kc * 64;
                for (int c4 = 0; c4 < 16; ++c4) {
                    int c = c4 * 4;
                    float x0 = Xs[c][w], x1 = Xs[c + 1][w];
                    float x2 = Xs[c + 2][w], x3 = Xs[c + 3][w];
#pragma unroll
                    for (int r = 0; r < 17; ++r) {
                        float4 wv = *(const float4*)&wp[r * CIN + c];
                        int ch = chb * 17 + r;    // compile-time after unroll
                        acc[ch] = fmaf(wv.x, x0, fmaf(wv.y, x1,
                                  fmaf(wv.z, x2, fmaf(wv.w, x3, acc[ch]))));
                    }
                }
            }
        }
    }

    float part[5] = {0.f, 0.f, 0.f, 0.f, 0.f};   // xy, wh, obj, cls, l2
    if (t < 228) {
#pragma unroll
        for (int i = 0; i < NCH; i++) acc[i] += bias[a * NCH + i];

        const float manw[3] = {1.25f, 2.0f, 4.125f};
        const float manh[3] = {1.625f, 3.75f, 2.875f};
        float s0 = sigm(acc[0]), s1 = sigm(acc[1]), s4 = sigm(acc[4]);
        float pw = expf(acc[2]) * manw[a];
        float ph = expf(acc[3]) * manh[a];
        float px = s0 + (float)w, py = s1 + (float)h;
        float parea = pw * ph;
        float ptlx = px - 0.5f * pw, ptly = py - 0.5f * ph;
        float pbrx = px + 0.5f * pw, pbry = py + 0.5f * ph;

        float maxiou = -1e30f;
        int aidx = -1;
        for (int k = 0; k < KLAB; k++) {
            const float* r = &Lb[k * 16];
            float tlx = fmaxf(ptlx, r[0]), tly = fmaxf(ptly, r[1]);
            float brx = fminf(pbrx, r[2]), bry = fminf(pbry, r[3]);
            float inter = ((tlx < brx) && (tly < bry)) ? (brx - tlx) * (bry - tly) : 0.0f;
            float iou = (r[5] != 0.0f) ? inter / (parea + r[4] - inter) : 0.0f;
            maxiou = fmaxf(maxiou, iou);
            if (r[12] != 0.0f && (int)r[13] == a && (int)r[14] == w && (int)r[15] == h)
                aidx = k;                 // last match wins (sequential scatter order)
        }

        if (aidx >= 0) {
            const float* r = &Lb[aidx * 16];
            float sc = r[11], sc2 = sc * sc;
            part[0] += sc2 * (bce_full(s0, r[6]) + bce_full(s1, r[7]));
            float dw = acc[2] - r[8], dh = acc[3] - r[9];
            float whq = dw * dw + dh * dh;
            part[1] += 0.5f * sc2 * whq;
            part[2] += bce1(s4);
            int ci = (int)r[10];
            float l2 = (s0 - r[6]) * (s0 - r[6]) + (s1 - r[7]) * (s1 - r[7]) +
                       sc2 * whq + (s4 - 1.0f) * (s4 - 1.0f);
            float lcls = 0.0f;
            for (int c = 0; c < NCLS; c++) {
                float s = sigm(acc[5 + c]);
                if (c == ci) { lcls += bce1(s); l2 += (s - 1.0f) * (s - 1.0f); }
                else         { lcls += bce0(s); l2 += s * s; }
            }
            part[3] += lcls;
            part[4] += l2;
        } else {
            bool objm = !(maxiou > 0.7f);
            if (objm) { part[2] += bce0(s4); part[4] += s4 * s4; }
        }
    }

    // block reduction: wave shuffle then cross-wave via LDS
#pragma unroll
    for (int i = 0; i < 5; i++) {
        float v = part[i];
        for (int off = 32; off > 0; off >>= 1) v += __shfl_down(v, off);
        if ((t & 63) == 0) red[t >> 6][i] = v;
    }
    __syncthreads();
    if (t == 0) {
#pragma unroll
        for (int i = 0; i < 5; i++) {
            float s = red[0][i] + red[1][i] + red[2][i] + red[3][i];
            atomicAdd(&accum[i], s);
        }
    }
}

__global__ void yolo_fin(const float* __restrict__ accum, float* __restrict__ out) {
    if (threadIdx.x == 0 && blockIdx.x == 0) {
        float xy = accum[0], wh = accum[1], obj = accum[2], cls = accum[3], l2 = accum[4];
        out[0] = xy + wh + obj + cls;
        out[1] = xy; out[2] = wh; out[3] = obj; out[4] = cls; out[5] = l2;
    }
}

extern "C" void kernel_launch(void* const* d_in, const int* in_sizes, int n_in,
                              void* d_out, int out_size, void* d_ws, size_t ws_size,
                              hipStream_t stream) {
    const float* xin    = (const float*)d_in[0];
    const float* labels = (const float*)d_in[1];
    const float* Wm     = (const float*)d_in[2];
    const float* bias   = (const float*)d_in[3];
    float* out = (float*)d_out;

    float* accum = (float*)d_ws;
    float* lrec  = (float*)((char*)d_ws + 256);

    hipMemsetAsync(d_ws, 0, 256, stream);
    yolo_lab<<<(NB * KLAB + 63) / 64, 64, 0, stream>>>(labels, lrec);
    yolo_main<<<NB * FDIM, 256, 0, stream>>>(xin, Wm, bias, lrec, accum);
    yolo_fin<<<1, 64, 0, stream>>>(accum, out);
}

// Round 2
// 167.128 us; speedup vs baseline: 6.7482x; 6.7482x over previous
//
#include <hip/hip_runtime.h>
#include <math.h>

typedef unsigned int u32;
typedef unsigned short u16;
typedef __attribute__((ext_vector_type(2))) u32 u32x2;
typedef __attribute__((ext_vector_type(4))) u32 u32x4;
typedef __attribute__((ext_vector_type(8))) short bf16x8;
typedef __attribute__((ext_vector_type(4))) float f32x4;

#define FDIM 76
#define NCELL 5776
#define NA 3
#define NCH 85
#define NCLS 80
#define KLAB 40
#define NB 16
#define CIN 256
#define TILES_PER_B 91   // 90*64 + 16 = 5776

__device__ __forceinline__ float sigm(float x) { return 1.0f / (1.0f + expf(-x)); }
__device__ __forceinline__ float bce_full(float p, float t) {
    return -(t * fmaxf(logf(p), -100.0f) + (1.0f - t) * fmaxf(logf(1.0f - p), -100.0f));
}
__device__ __forceinline__ float bce1(float p) { return -fmaxf(logf(p), -100.0f); }
__device__ __forceinline__ float bce0(float p) { return -fmaxf(logf(1.0f - p), -100.0f); }

__device__ __forceinline__ u16 bf16rne(float f) {
    u32 u = __float_as_uint(f);
    u32 r = u + 0x7fffu + ((u >> 16) & 1u);
    return (u16)(r >> 16);
}

// ---- W fp32 -> bf16, padded to [256][256] (row 255 zero) ----
__global__ __launch_bounds__(256) void yolo_wconv(const float* __restrict__ W,
                                                  u16* __restrict__ Wbf) {
    int idx = blockIdx.x * 256 + threadIdx.x;   // 0..65535
    int row = idx >> 8, col = idx & 255;
    float v = (row < NA * NCH) ? W[row * CIN + col] : 0.0f;
    Wbf[idx] = bf16rne(v);
}

// ---- label prep (verified exact in round 1) ----
__global__ __launch_bounds__(64) void yolo_lab(const float* __restrict__ labels,
                                               float* __restrict__ lrec) {
    int idx = blockIdx.x * 64 + threadIdx.x;
    if (idx >= NB * KLAB) return;
    const float* l = labels + idx * 5;
    float cls = l[0], x = l[1], y = l[2], ww = l[3], hh = l[4];
    bool valid = (cls + x + y + ww + hh) > 0.0f;
    float tx = x * FDIM, ty = y * FDIM, tw = ww * FDIM, th = hh * FDIM;
    int ti = (int)tx, tj = (int)ty;
    float area_a = (tw - tx) * (th - ty);
    const float aw[9] = {1.25f, 2.0f, 4.125f, 3.75f, 7.75f, 7.375f, 14.5f, 19.5f, 46.625f};
    const float ah[9] = {1.625f, 3.75f, 2.875f, 7.625f, 5.625f, 14.875f, 11.25f, 24.75f, 40.75f};
    float best = -1e30f;
    int bi = 0;
    for (int n = 0; n < 9; n++) {
        float bw = fminf(tw, aw[n]), bh = fminf(th, ah[n]);
        float ai = ((tx < bw) && (ty < bh)) ? (bw - tx) * (bh - ty) : 0.0f;
        float iou = valid ? ai / (area_a + aw[n] * ah[n] - ai) : -1.0f;
        if (iou > best) { best = iou; bi = n; }
    }
    int bn = bi % 3;
    bool assign = valid && (bi < 3);
    float* r = lrec + idx * 16;
    r[0] = tx - 0.5f * tw; r[1] = ty - 0.5f * th;
    r[2] = tx + 0.5f * tw; r[3] = ty + 0.5f * th;
    r[4] = tw * th; r[5] = valid ? 1.0f : 0.0f;
    r[6] = tx - (float)ti; r[7] = ty - (float)tj;
    r[8] = logf(tw / aw[bn] + 1e-16f); r[9] = logf(th / ah[bn] + 1e-16f);
    r[10] = cls; r[11] = sqrtf(2.0f - tw * th / (float)(FDIM * FDIM));
    r[12] = assign ? 1.0f : 0.0f; r[13] = (float)bn; r[14] = (float)ti; r[15] = (float)tj;
}

// ---- fused MFMA GEMM + loss ----
__global__ __launch_bounds__(256) void yolo_mfma(const float* __restrict__ xin,
                                                 const u16* __restrict__ Wbf,
                                                 const float* __restrict__ bias,
                                                 const float* __restrict__ lrec,
                                                 float* __restrict__ accum) {
    __shared__ char smem[66560];        // GEMM: Ws 32768 + Xs 8192 ; epilogue: Cs [256][65] f32
    __shared__ float Lb[KLAB * 16];
    __shared__ float red[4][8];

    u16* Ws = (u16*)smem;               // [256 ch][64 k] bf16, XOR-swizzled rows (128 B)
    u16* Xs = (u16*)(smem + 32768);     // [64 cell][64 k] bf16, XOR-swizzled rows
    float* Cs = (float*)smem;           // [256][65]

    const int blk = blockIdx.x;
    const int b = blk / TILES_PER_B;
    const int tile = blk - b * TILES_PER_B;
    const int cell0 = tile * 64;
    const int t = threadIdx.x;
    const int lane = t & 63;
    const int wid = t >> 6;
    const int g = lane >> 4;
    const int l15 = lane & 15;

    for (int i = t; i < KLAB * 16; i += 256) Lb[i] = lrec[b * KLAB * 16 + i];

    f32x4 acc[4][4];
#pragma unroll
    for (int mi = 0; mi < 4; mi++)
#pragma unroll
        for (int ni = 0; ni < 4; ni++) acc[mi][ni] = (f32x4){0.f, 0.f, 0.f, 0.f};

    for (int kc = 0; kc < 4; kc++) {
        __syncthreads();
        // stage W chunk: Ws[r][k] = Wbf[r][kc*64+k]
#pragma unroll
        for (int ii = 0; ii < 8; ii++) {
            int i = t + ii * 256;                 // 0..2047 (16B segments)
            int r = i >> 3, seg = i & 7;
            u32x4 v = *(const u32x4*)(Wbf + r * CIN + kc * 64 + seg * 8);
            int byte = (r * 128 + seg * 16) ^ ((r & 7) << 4);
            *(u32x4*)((char*)Ws + byte) = v;
        }
        // stage X chunk transposed: Xs[cell][k] = bf16(xin[b][kc*64+k][cell0+cell])
#pragma unroll
        for (int ii = 0; ii < 4; ii++) {
            int u = t + ii * 256;                 // 0..1023 (k-quads)
            int kq = u >> 6, cell = u & 63;
            int cg = cell0 + cell;
            const float* xp = xin + ((size_t)(b * CIN + kc * 64 + kq * 4)) * NCELL + cg;
            float x0 = 0.f, x1 = 0.f, x2 = 0.f, x3 = 0.f;
            if (cg < NCELL) { x0 = xp[0]; x1 = xp[NCELL]; x2 = xp[2 * NCELL]; x3 = xp[3 * NCELL]; }
            u32x2 pv;
            pv.x = (u32)bf16rne(x0) | ((u32)bf16rne(x1) << 16);
            pv.y = (u32)bf16rne(x2) | ((u32)bf16rne(x3) << 16);
            int byte = (cell * 128 + kq * 8) ^ ((cell & 7) << 4);
            *(u32x2*)((char*)Xs + byte) = pv;
        }
        __syncthreads();
#pragma unroll
        for (int s = 0; s < 2; s++) {
            bf16x8 af[4], bfr[4];
#pragma unroll
            for (int mi = 0; mi < 4; mi++) {
                int ch = wid * 64 + mi * 16 + l15;
                int byte = (ch * 128 + s * 64 + g * 16) ^ ((ch & 7) << 4);
                af[mi] = *(const bf16x8*)((char*)Ws + byte);
            }
#pragma unroll
            for (int ni = 0; ni < 4; ni++) {
                int cell = ni * 16 + l15;
                int byte = (cell * 128 + s * 64 + g * 16) ^ ((cell & 7) << 4);
                bfr[ni] = *(const bf16x8*)((char*)Xs + byte);
            }
#pragma unroll
            for (int mi = 0; mi < 4; mi++)
#pragma unroll
                for (int ni = 0; ni < 4; ni++)
                    acc[mi][ni] = __builtin_amdgcn_mfma_f32_16x16x32_bf16(
                        af[mi], bfr[ni], acc[mi][ni], 0, 0, 0);
        }
    }
    __syncthreads();
    // C -> LDS [256][65]
#pragma unroll
    for (int mi = 0; mi < 4; mi++)
#pragma unroll
        for (int ni = 0; ni < 4; ni++)
#pragma unroll
            for (int reg = 0; reg < 4; reg++) {
                int ch = wid * 64 + mi * 16 + g * 4 + reg;
                int cell = ni * 16 + l15;
                Cs[ch * 65 + cell] = acc[mi][ni][reg];
            }
    __syncthreads();

    // ---- loss epilogue (round-1 verified math) ----
    float part[5] = {0.f, 0.f, 0.f, 0.f, 0.f};
    if (t < 192) {
        int a = t >> 6;
        int c = t & 63;
        int cg = cell0 + c;
        if (cg < NCELL) {
            int hh = cg / FDIM;
            int ww = cg - hh * FDIM;
            const int chb = a * NCH;
            float v0 = Cs[(chb + 0) * 65 + c] + bias[chb + 0];
            float v1 = Cs[(chb + 1) * 65 + c] + bias[chb + 1];
            float v2 = Cs[(chb + 2) * 65 + c] + bias[chb + 2];
            float v3 = Cs[(chb + 3) * 65 + c] + bias[chb + 3];
            float v4 = Cs[(chb + 4) * 65 + c] + bias[chb + 4];
            const float manw[3] = {1.25f, 2.0f, 4.125f};
            const float manh[3] = {1.625f, 3.75f, 2.875f};
            float s0 = sigm(v0), s1 = sigm(v1), s4 = sigm(v4);
            float pw = expf(v2) * manw[a];
            float ph = expf(v3) * manh[a];
            float px = s0 + (float)ww, py = s1 + (float)hh;
            float parea = pw * ph;
            float ptlx = px - 0.5f * pw, ptly = py - 0.5f * ph;
            float pbrx = px + 0.5f * pw, pbry = py + 0.5f * ph;

            float maxiou = -1e30f;
            int aidx = -1;
            for (int k = 0; k < KLAB; k++) {
                const float* r = &Lb[k * 16];
                float tlx = fmaxf(ptlx, r[0]), tly = fmaxf(ptly, r[1]);
                float brx = fminf(pbrx, r[2]), bry = fminf(pbry, r[3]);
                float inter = ((tlx < brx) && (tly < bry)) ? (brx - tlx) * (bry - tly) : 0.0f;
                float iou = (r[5] != 0.0f) ? inter / (parea + r[4] - inter) : 0.0f;
                maxiou = fmaxf(maxiou, iou);
                if (r[12] != 0.0f && (int)r[13] == a && (int)r[14] == ww && (int)r[15] == hh)
                    aidx = k;             // last match wins
            }

            if (aidx >= 0) {
                const float* r = &Lb[aidx * 16];
                float sc = r[11], sc2 = sc * sc;
                part[0] += sc2 * (bce_full(s0, r[6]) + bce_full(s1, r[7]));
                float dw = v2 - r[8], dh = v3 - r[9];
                float whq = dw * dw + dh * dh;
                part[1] += 0.5f * sc2 * whq;
                part[2] += bce1(s4);
                int ci = (int)r[10];
                float l2 = (s0 - r[6]) * (s0 - r[6]) + (s1 - r[7]) * (s1 - r[7]) +
                           sc2 * whq + (s4 - 1.0f) * (s4 - 1.0f);
                float lcls = 0.0f;
                for (int cc = 0; cc < NCLS; cc++) {
                    float s = sigm(Cs[(chb + 5 + cc) * 65 + c] + bias[chb + 5 + cc]);
                    if (cc == ci) { lcls += bce1(s); l2 += (s - 1.0f) * (s - 1.0f); }
                    else          { lcls += bce0(s); l2 += s * s; }
                }
                part[3] += lcls;
                part[4] += l2;
            } else {
                bool objm = !(maxiou > 0.7f);
                if (objm) { part[2] += bce0(s4); part[4] += s4 * s4; }
            }
        }
    }

#pragma unroll
    for (int i = 0; i < 5; i++) {
        float v = part[i];
        for (int off = 32; off > 0; off >>= 1) v += __shfl_down(v, off);
        if ((t & 63) == 0) red[t >> 6][i] = v;
    }
    __syncthreads();
    if (t == 0) {
#pragma unroll
        for (int i = 0; i < 5; i++) {
            float s = red[0][i] + red[1][i] + red[2][i] + red[3][i];
            atomicAdd(&accum[i], s);
        }
    }
}

__global__ void yolo_fin(const float* __restrict__ accum, float* __restrict__ out) {
    if (threadIdx.x == 0 && blockIdx.x == 0) {
        float xy = accum[0], wh = accum[1], obj = accum[2], cls = accum[3], l2 = accum[4];
        out[0] = xy + wh + obj + cls;
        out[1] = xy; out[2] = wh; out[3] = obj; out[4] = cls; out[5] = l2;
    }
}

extern "C" void kernel_launch(void* const* d_in, const int* in_sizes, int n_in,
                              void* d_out, int out_size, void* d_ws, size_t ws_size,
                              hipStream_t stream) {
    const float* xin    = (const float*)d_in[0];
    const float* labels = (const float*)d_in[1];
    const float* Wm     = (const float*)d_in[2];
    const float* bias   = (const float*)d_in[3];
    float* out = (float*)d_out;

    float* accum = (float*)d_ws;                         // 256 B
    float* lrec  = (float*)((char*)d_ws + 256);          // 40960 B
    u16*   Wbf   = (u16*)((char*)d_ws + 41216);          // 131072 B

    hipMemsetAsync(d_ws, 0, 256, stream);
    yolo_wconv<<<256, 256, 0, stream>>>(Wm, Wbf);
    yolo_lab<<<(NB * KLAB + 63) / 64, 64, 0, stream>>>(labels, lrec);
    yolo_mfma<<<NB * TILES_PER_B, 256, 0, stream>>>(xin, Wbf, bias, lrec, accum);
    yolo_fin<<<1, 64, 0, stream>>>(accum, out);
}

// Round 3
// 143.537 us; speedup vs baseline: 7.8573x; 1.1644x over previous
//
#include <hip/hip_runtime.h>
#include <math.h>

typedef unsigned int u32;
typedef unsigned short u16;
typedef __attribute__((ext_vector_type(2))) u32 u32x2;
typedef __attribute__((ext_vector_type(4))) u32 u32x4;
typedef __attribute__((ext_vector_type(8))) short bf16x8;
typedef __attribute__((ext_vector_type(4))) float f32x4;

#define FDIM 76
#define NCELL 5776
#define NA 3
#define NCH 85
#define NCLS 80
#define KLAB 40
#define NB 16
#define CIN 256
#define TILES_PER_B 91   // 91*64 >= 5776
#define NBLK (NB * TILES_PER_B)   // 1456

__device__ __forceinline__ float sigm(float x) { return 1.0f / (1.0f + expf(-x)); }
__device__ __forceinline__ float bce_full(float p, float t) {
    return -(t * fmaxf(logf(p), -100.0f) + (1.0f - t) * fmaxf(logf(1.0f - p), -100.0f));
}
__device__ __forceinline__ float bce1(float p) { return -fmaxf(logf(p), -100.0f); }
__device__ __forceinline__ float bce0(float p) { return -fmaxf(logf(1.0f - p), -100.0f); }

__device__ __forceinline__ u16 bf16rne(float f) {
    u32 u = __float_as_uint(f);
    u32 r = u + 0x7fffu + ((u >> 16) & 1u);
    return (u16)(r >> 16);
}

// ---- W fp32 -> bf16, padded to [256][256] (row 255 zero) ----
__global__ __launch_bounds__(256) void yolo_wconv(const float* __restrict__ W,
                                                  u16* __restrict__ Wbf) {
    int idx = blockIdx.x * 256 + threadIdx.x;   // 0..65535
    int row = idx >> 8, col = idx & 255;
    float v = (row < NA * NCH) ? W[row * CIN + col] : 0.0f;
    Wbf[idx] = bf16rne(v);
}

// ---- label prep (verified exact in round 1) ----
__global__ __launch_bounds__(64) void yolo_lab(const float* __restrict__ labels,
                                               float* __restrict__ lrec) {
    int idx = blockIdx.x * 64 + threadIdx.x;
    if (idx >= NB * KLAB) return;
    const float* l = labels + idx * 5;
    float cls = l[0], x = l[1], y = l[2], ww = l[3], hh = l[4];
    bool valid = (cls + x + y + ww + hh) > 0.0f;
    float tx = x * FDIM, ty = y * FDIM, tw = ww * FDIM, th = hh * FDIM;
    int ti = (int)tx, tj = (int)ty;
    float area_a = (tw - tx) * (th - ty);
    const float aw[9] = {1.25f, 2.0f, 4.125f, 3.75f, 7.75f, 7.375f, 14.5f, 19.5f, 46.625f};
    const float ah[9] = {1.625f, 3.75f, 2.875f, 7.625f, 5.625f, 14.875f, 11.25f, 24.75f, 40.75f};
    float best = -1e30f;
    int bi = 0;
    for (int n = 0; n < 9; n++) {
        float bw = fminf(tw, aw[n]), bh = fminf(th, ah[n]);
        float ai = ((tx < bw) && (ty < bh)) ? (bw - tx) * (bh - ty) : 0.0f;
        float iou = valid ? ai / (area_a + aw[n] * ah[n] - ai) : -1.0f;
        if (iou > best) { best = iou; bi = n; }
    }
    int bn = bi % 3;
    bool assign = valid && (bi < 3);
    float* r = lrec + idx * 16;
    r[0] = tx - 0.5f * tw; r[1] = ty - 0.5f * th;
    r[2] = tx + 0.5f * tw; r[3] = ty + 0.5f * th;
    r[4] = tw * th; r[5] = valid ? 1.0f : 0.0f;
    r[6] = tx - (float)ti; r[7] = ty - (float)tj;
    r[8] = logf(tw / aw[bn] + 1e-16f); r[9] = logf(th / ah[bn] + 1e-16f);
    r[10] = cls; r[11] = sqrtf(2.0f - tw * th / (float)(FDIM * FDIM));
    r[12] = assign ? 1.0f : 0.0f; r[13] = (float)bn; r[14] = (float)ti; r[15] = (float)tj;
}

// ---- fused MFMA GEMM + loss; per-block partials, NO atomics ----
__global__ __launch_bounds__(256) void yolo_mfma(const float* __restrict__ xin,
                                                 const u16* __restrict__ Wbf,
                                                 const float* __restrict__ bias,
                                                 const float* __restrict__ lrec,
                                                 float* __restrict__ partials) {
    __shared__ char smem[66560];        // GEMM: Ws 32768 + Xs 8192 ; epilogue: Cs [256][65] f32
    __shared__ float Lb[KLAB * 16];
    __shared__ float red[4][8];

    u16* Ws = (u16*)smem;               // [256 ch][64 k] bf16, XOR-swizzled rows (128 B)
    u16* Xs = (u16*)(smem + 32768);     // [64 cell][64 k] bf16, XOR-swizzled rows
    float* Cs = (float*)smem;           // [256][65]

    const int blk = blockIdx.x;
    const int b = blk / TILES_PER_B;
    const int tile = blk - b * TILES_PER_B;
    const int cell0 = tile * 64;
    const int t = threadIdx.x;
    const int lane = t & 63;
    const int wid = t >> 6;
    const int g = lane >> 4;
    const int l15 = lane & 15;

    for (int i = t; i < KLAB * 16; i += 256) Lb[i] = lrec[b * KLAB * 16 + i];

    f32x4 acc[4][4];
#pragma unroll
    for (int mi = 0; mi < 4; mi++)
#pragma unroll
        for (int ni = 0; ni < 4; ni++) acc[mi][ni] = (f32x4){0.f, 0.f, 0.f, 0.f};

    for (int kc = 0; kc < 4; kc++) {
        __syncthreads();
        // stage W chunk: Ws[r][k] = Wbf[r][kc*64+k]
#pragma unroll
        for (int ii = 0; ii < 8; ii++) {
            int i = t + ii * 256;                 // 0..2047 (16B segments)
            int r = i >> 3, seg = i & 7;
            u32x4 v = *(const u32x4*)(Wbf + r * CIN + kc * 64 + seg * 8);
            int byte = (r * 128 + seg * 16) ^ ((r & 7) << 4);
            *(u32x4*)((char*)Ws + byte) = v;
        }
        // stage X chunk transposed: Xs[cell][k] = bf16(xin[b][kc*64+k][cell0+cell])
#pragma unroll
        for (int ii = 0; ii < 4; ii++) {
            int u = t + ii * 256;                 // 0..1023 (k-quads)
            int kq = u >> 6, cell = u & 63;
            int cg = cell0 + cell;
            const float* xp = xin + ((size_t)(b * CIN + kc * 64 + kq * 4)) * NCELL + cg;
            float x0 = 0.f, x1 = 0.f, x2 = 0.f, x3 = 0.f;
            if (cg < NCELL) { x0 = xp[0]; x1 = xp[NCELL]; x2 = xp[2 * NCELL]; x3 = xp[3 * NCELL]; }
            u32x2 pv;
            pv.x = (u32)bf16rne(x0) | ((u32)bf16rne(x1) << 16);
            pv.y = (u32)bf16rne(x2) | ((u32)bf16rne(x3) << 16);
            int byte = (cell * 128 + kq * 8) ^ ((cell & 7) << 4);
            *(u32x2*)((char*)Xs + byte) = pv;
        }
        __syncthreads();
#pragma unroll
        for (int s = 0; s < 2; s++) {
            bf16x8 af[4], bfr[4];
#pragma unroll
            for (int mi = 0; mi < 4; mi++) {
                int ch = wid * 64 + mi * 16 + l15;
                int byte = (ch * 128 + s * 64 + g * 16) ^ ((ch & 7) << 4);
                af[mi] = *(const bf16x8*)((char*)Ws + byte);
            }
#pragma unroll
            for (int ni = 0; ni < 4; ni++) {
                int cell = ni * 16 + l15;
                int byte = (cell * 128 + s * 64 + g * 16) ^ ((cell & 7) << 4);
                bfr[ni] = *(const bf16x8*)((char*)Xs + byte);
            }
#pragma unroll
            for (int mi = 0; mi < 4; mi++)
#pragma unroll
                for (int ni = 0; ni < 4; ni++)
                    acc[mi][ni] = __builtin_amdgcn_mfma_f32_16x16x32_bf16(
                        af[mi], bfr[ni], acc[mi][ni], 0, 0, 0);
        }
    }
    __syncthreads();
    // C -> LDS [256][65]
#pragma unroll
    for (int mi = 0; mi < 4; mi++)
#pragma unroll
        for (int ni = 0; ni < 4; ni++)
#pragma unroll
            for (int reg = 0; reg < 4; reg++) {
                int ch = wid * 64 + mi * 16 + g * 4 + reg;
                int cell = ni * 16 + l15;
                Cs[ch * 65 + cell] = acc[mi][ni][reg];
            }
    __syncthreads();

    // ---- loss epilogue (round-1 verified math) ----
    float part[5] = {0.f, 0.f, 0.f, 0.f, 0.f};
    if (t < 192) {
        int a = t >> 6;
        int c = t & 63;
        int cg = cell0 + c;
        if (cg < NCELL) {
            int hh = cg / FDIM;
            int ww = cg - hh * FDIM;
            const int chb = a * NCH;
            float v0 = Cs[(chb + 0) * 65 + c] + bias[chb + 0];
            float v1 = Cs[(chb + 1) * 65 + c] + bias[chb + 1];
            float v2 = Cs[(chb + 2) * 65 + c] + bias[chb + 2];
            float v3 = Cs[(chb + 3) * 65 + c] + bias[chb + 3];
            float v4 = Cs[(chb + 4) * 65 + c] + bias[chb + 4];
            const float manw[3] = {1.25f, 2.0f, 4.125f};
            const float manh[3] = {1.625f, 3.75f, 2.875f};
            float s0 = sigm(v0), s1 = sigm(v1), s4 = sigm(v4);
            float pw = expf(v2) * manw[a];
            float ph = expf(v3) * manh[a];
            float px = s0 + (float)ww, py = s1 + (float)hh;
            float parea = pw * ph;
            float ptlx = px - 0.5f * pw, ptly = py - 0.5f * ph;
            float pbrx = px + 0.5f * pw, pbry = py + 0.5f * ph;

            float maxiou = -1e30f;
            int aidx = -1;
            for (int k = 0; k < KLAB; k++) {
                const float* r = &Lb[k * 16];
                float tlx = fmaxf(ptlx, r[0]), tly = fmaxf(ptly, r[1]);
                float brx = fminf(pbrx, r[2]), bry = fminf(pbry, r[3]);
                float inter = ((tlx < brx) && (tly < bry)) ? (brx - tlx) * (bry - tly) : 0.0f;
                float iou = (r[5] != 0.0f) ? inter / (parea + r[4] - inter) : 0.0f;
                maxiou = fmaxf(maxiou, iou);
                if (r[12] != 0.0f && (int)r[13] == a && (int)r[14] == ww && (int)r[15] == hh)
                    aidx = k;             // last match wins
            }

            if (aidx >= 0) {
                const float* r = &Lb[aidx * 16];
                float sc = r[11], sc2 = sc * sc;
                part[0] += sc2 * (bce_full(s0, r[6]) + bce_full(s1, r[7]));
                float dw = v2 - r[8], dh = v3 - r[9];
                float whq = dw * dw + dh * dh;
                part[1] += 0.5f * sc2 * whq;
                part[2] += bce1(s4);
                int ci = (int)r[10];
                float l2 = (s0 - r[6]) * (s0 - r[6]) + (s1 - r[7]) * (s1 - r[7]) +
                           sc2 * whq + (s4 - 1.0f) * (s4 - 1.0f);
                float lcls = 0.0f;
                for (int cc = 0; cc < NCLS; cc++) {
                    float s = sigm(Cs[(chb + 5 + cc) * 65 + c] + bias[chb + 5 + cc]);
                    if (cc == ci) { lcls += bce1(s); l2 += (s - 1.0f) * (s - 1.0f); }
                    else          { lcls += bce0(s); l2 += s * s; }
                }
                part[3] += lcls;
                part[4] += l2;
            } else {
                bool objm = !(maxiou > 0.7f);
                if (objm) { part[2] += bce0(s4); part[4] += s4 * s4; }
            }
        }
    }

#pragma unroll
    for (int i = 0; i < 5; i++) {
        float v = part[i];
        for (int off = 32; off > 0; off >>= 1) v += __shfl_down(v, off);
        if ((t & 63) == 0) red[t >> 6][i] = v;
    }
    __syncthreads();
    if (t == 0) {
#pragma unroll
        for (int i = 0; i < 5; i++)
            partials[blk * 8 + i] = red[0][i] + red[1][i] + red[2][i] + red[3][i];
    }
}

// ---- final reduction over per-block partials (no atomics anywhere) ----
__global__ __launch_bounds__(256) void yolo_fin(const float* __restrict__ partials,
                                                float* __restrict__ out) {
    __shared__ float red[4][8];
    const int t = threadIdx.x;
    float s[5] = {0.f, 0.f, 0.f, 0.f, 0.f};
    for (int r = t; r < NBLK; r += 256)
#pragma unroll
        for (int i = 0; i < 5; i++) s[i] += partials[r * 8 + i];
#pragma unroll
    for (int i = 0; i < 5; i++) {
        float v = s[i];
        for (int off = 32; off > 0; off >>= 1) v += __shfl_down(v, off);
        if ((t & 63) == 0) red[t >> 6][i] = v;
    }
    __syncthreads();
    if (t == 0) {
        float xy  = red[0][0] + red[1][0] + red[2][0] + red[3][0];
        float wh  = red[0][1] + red[1][1] + red[2][1] + red[3][1];
        float obj = red[0][2] + red[1][2] + red[2][2] + red[3][2];
        float cls = red[0][3] + red[1][3] + red[2][3] + red[3][3];
        float l2  = red[0][4] + red[1][4] + red[2][4] + red[3][4];
        out[0] = xy + wh + obj + cls;
        out[1] = xy; out[2] = wh; out[3] = obj; out[4] = cls; out[5] = l2;
    }
}

extern "C" void kernel_launch(void* const* d_in, const int* in_sizes, int n_in,
                              void* d_out, int out_size, void* d_ws, size_t ws_size,
                              hipStream_t stream) {
    const float* xin    = (const float*)d_in[0];
    const float* labels = (const float*)d_in[1];
    const float* Wm     = (const float*)d_in[2];
    const float* bias   = (const float*)d_in[3];
    float* out = (float*)d_out;

    float* partials = (float*)d_ws;                            // 1456*8*4 = 46592 B
    float* lrec  = (float*)((char*)d_ws + 46592);              // 40960 B
    u16*   Wbf   = (u16*)((char*)d_ws + 46592 + 40960);        // 131072 B

    yolo_wconv<<<256, 256, 0, stream>>>(Wm, Wbf);
    yolo_lab<<<(NB * KLAB + 63) / 64, 64, 0, stream>>>(labels, lrec);
    yolo_mfma<<<NBLK, 256, 0, stream>>>(xin, Wbf, bias, lrec, partials);
    yolo_fin<<<1, 256, 0, stream>>>(partials, out);
}

// Round 4
// 101.614 us; speedup vs baseline: 11.0989x; 1.4126x over previous
//
#include <hip/hip_runtime.h>
#include <math.h>

typedef unsigned int u32;
typedef unsigned short u16;
typedef __attribute__((ext_vector_type(2))) u32 u32x2;
typedef __attribute__((ext_vector_type(4))) u32 u32x4;
typedef __attribute__((ext_vector_type(8))) short bf16x8;
typedef __attribute__((ext_vector_type(4))) float f32x4;

#define FDIM 76
#define NCELL 5776
#define NA 3
#define NCH 85
#define NCLS 80
#define KLAB 40
#define NB 16
#define CIN 256
#define TILES_PER_B 91
#define NBLK (NB * TILES_PER_B)   // 1456
#define CS_LD 68                  // Cs row stride in u16

__device__ __forceinline__ float sigm(float x) { return 1.0f / (1.0f + expf(-x)); }
__device__ __forceinline__ float bce_full(float p, float t) {
    return -(t * fmaxf(logf(p), -100.0f) + (1.0f - t) * fmaxf(logf(1.0f - p), -100.0f));
}
__device__ __forceinline__ float bce1(float p) { return -fmaxf(logf(p), -100.0f); }
__device__ __forceinline__ float bce0(float p) { return -fmaxf(logf(1.0f - p), -100.0f); }

__device__ __forceinline__ u16 bf16rne(float f) {
    u32 u = __float_as_uint(f);
    u32 r = u + 0x7fffu + ((u >> 16) & 1u);
    return (u16)(r >> 16);
}
__device__ __forceinline__ float bf16f(u16 v) { return __uint_as_float(((u32)v) << 16); }

// ---- W fp32 -> bf16, padded to [256][256] (row 255 zero) ----
__global__ __launch_bounds__(256) void yolo_wconv(const float* __restrict__ W,
                                                  u16* __restrict__ Wbf) {
    int idx = blockIdx.x * 256 + threadIdx.x;
    int row = idx >> 8, col = idx & 255;
    float v = (row < NA * NCH) ? W[row * CIN + col] : 0.0f;
    Wbf[idx] = bf16rne(v);
}

// ---- label prep (verified exact) ----
__global__ __launch_bounds__(64) void yolo_lab(const float* __restrict__ labels,
                                               float* __restrict__ lrec) {
    int idx = blockIdx.x * 64 + threadIdx.x;
    if (idx >= NB * KLAB) return;
    const float* l = labels + idx * 5;
    float cls = l[0], x = l[1], y = l[2], ww = l[3], hh = l[4];
    bool valid = (cls + x + y + ww + hh) > 0.0f;
    float tx = x * FDIM, ty = y * FDIM, tw = ww * FDIM, th = hh * FDIM;
    int ti = (int)tx, tj = (int)ty;
    float area_a = (tw - tx) * (th - ty);
    const float aw[9] = {1.25f, 2.0f, 4.125f, 3.75f, 7.75f, 7.375f, 14.5f, 19.5f, 46.625f};
    const float ah[9] = {1.625f, 3.75f, 2.875f, 7.625f, 5.625f, 14.875f, 11.25f, 24.75f, 40.75f};
    float best = -1e30f;
    int bi = 0;
    for (int n = 0; n < 9; n++) {
        float bw = fminf(tw, aw[n]), bh = fminf(th, ah[n]);
        float ai = ((tx < bw) && (ty < bh)) ? (bw - tx) * (bh - ty) : 0.0f;
        float iou = valid ? ai / (area_a + aw[n] * ah[n] - ai) : -1.0f;
        if (iou > best) { best = iou; bi = n; }
    }
    int bn = bi % 3;
    bool assign = valid && (bi < 3);
    float* r = lrec + idx * 16;
    r[0] = tx - 0.5f * tw; r[1] = ty - 0.5f * th;
    r[2] = tx + 0.5f * tw; r[3] = ty + 0.5f * th;
    r[4] = tw * th; r[5] = valid ? 1.0f : 0.0f;
    r[6] = tx - (float)ti; r[7] = ty - (float)tj;
    r[8] = logf(tw / aw[bn] + 1e-16f); r[9] = logf(th / ah[bn] + 1e-16f);
    r[10] = cls; r[11] = sqrtf(2.0f - tw * th / (float)(FDIM * FDIM));
    r[12] = assign ? 1.0f : 0.0f; r[13] = (float)bn; r[14] = (float)ti; r[15] = (float)tj;
}

// ---- fused MFMA GEMM + loss; batched branch-free staging; bf16 C tile ----
__global__ __launch_bounds__(256, 3) void yolo_mfma(const float* __restrict__ xin,
                                                    const u16* __restrict__ Wbf,
                                                    const float* __restrict__ bias,
                                                    const float* __restrict__ lrec,
                                                    float* __restrict__ partials) {
    __shared__ char smem[40960];        // GEMM: Ws 32768 + Xs 8192; epilogue: Csb [256][68] bf16 (34816)
    __shared__ float Lb[KLAB * 16];
    __shared__ float red[4][8];

    u16* Ws = (u16*)smem;               // [256 ch][64 k] bf16, XOR-swizzled rows (128 B)
    u16* Xs = (u16*)(smem + 32768);     // [64 cell][64 k] bf16, XOR-swizzled rows
    u16* Csb = (u16*)smem;              // [256][CS_LD] bf16, bias pre-added

    const int blk = blockIdx.x;
    const int b = blk / TILES_PER_B;
    const int tile = blk - b * TILES_PER_B;
    const int cell0 = tile * 64;
    const int t = threadIdx.x;
    const int lane = t & 63;
    const int wid = t >> 6;
    const int g = lane >> 4;
    const int l15 = lane & 15;

    for (int i = t; i < KLAB * 16; i += 256) Lb[i] = lrec[b * KLAB * 16 + i];

    f32x4 acc[4][4];
#pragma unroll
    for (int mi = 0; mi < 4; mi++)
#pragma unroll
        for (int ni = 0; ni < 4; ni++) acc[mi][ni] = (f32x4){0.f, 0.f, 0.f, 0.f};

    for (int kc = 0; kc < 4; kc++) {
        // ---- issue ALL global loads first (branch-free, before the barrier) ----
        float xv[16];
        u32x4 wv[8];
#pragma unroll
        for (int ii = 0; ii < 4; ii++) {
            const int u = t + ii * 256;
            const int kq = u >> 6, cell = u & 63;
            const int cg0 = cell0 + cell;
            const int cg = cg0 < NCELL ? cg0 : NCELL - 1;   // clamp: garbage cols masked later
            const float* xp = xin + ((size_t)(b * CIN + kc * 64 + kq * 4)) * NCELL + cg;
            xv[ii * 4 + 0] = xp[0];
            xv[ii * 4 + 1] = xp[NCELL];
            xv[ii * 4 + 2] = xp[2 * NCELL];
            xv[ii * 4 + 3] = xp[3 * NCELL];
        }
#pragma unroll
        for (int ii = 0; ii < 8; ii++) {
            const int i = t + ii * 256;
            const int r = i >> 3, seg = i & 7;
            wv[ii] = *(const u32x4*)(Wbf + r * CIN + kc * 64 + seg * 8);
        }
        __syncthreads();   // previous chunk's fragment reads complete; loads in flight across it
        // ---- LDS writes ----
#pragma unroll
        for (int ii = 0; ii < 8; ii++) {
            const int i = t + ii * 256;
            const int r = i >> 3, seg = i & 7;
            const int byte = (r * 128 + seg * 16) ^ ((r & 7) << 4);
            *(u32x4*)((char*)Ws + byte) = wv[ii];
        }
#pragma unroll
        for (int ii = 0; ii < 4; ii++) {
            const int u = t + ii * 256;
            const int kq = u >> 6, cell = u & 63;
            u32x2 pv;
            pv.x = (u32)bf16rne(xv[ii * 4 + 0]) | ((u32)bf16rne(xv[ii * 4 + 1]) << 16);
            pv.y = (u32)bf16rne(xv[ii * 4 + 2]) | ((u32)bf16rne(xv[ii * 4 + 3]) << 16);
            const int byte = (cell * 128 + kq * 8) ^ ((cell & 7) << 4);
            *(u32x2*)((char*)Xs + byte) = pv;
        }
        __syncthreads();
        // ---- fragment reads + MFMA ----
#pragma unroll
        for (int s = 0; s < 2; s++) {
            bf16x8 af[4], bfr[4];
#pragma unroll
            for (int mi = 0; mi < 4; mi++) {
                const int ch = wid * 64 + mi * 16 + l15;
                const int byte = (ch * 128 + s * 64 + g * 16) ^ ((ch & 7) << 4);
                af[mi] = *(const bf16x8*)((char*)Ws + byte);
            }
#pragma unroll
            for (int ni = 0; ni < 4; ni++) {
                const int cell = ni * 16 + l15;
                const int byte = (cell * 128 + s * 64 + g * 16) ^ ((cell & 7) << 4);
                bfr[ni] = *(const bf16x8*)((char*)Xs + byte);
            }
#pragma unroll
            for (int mi = 0; mi < 4; mi++)
#pragma unroll
                for (int ni = 0; ni < 4; ni++)
                    acc[mi][ni] = __builtin_amdgcn_mfma_f32_16x16x32_bf16(
                        af[mi], bfr[ni], acc[mi][ni], 0, 0, 0);
        }
    }

    // bias for this thread's 16 output channels (ch 255 is padding -> 0)
    float bv[16];
#pragma unroll
    for (int mi = 0; mi < 4; mi++)
#pragma unroll
        for (int reg = 0; reg < 4; reg++) {
            const int ch = wid * 64 + mi * 16 + g * 4 + reg;
            bv[mi * 4 + reg] = (ch < NA * NCH) ? bias[ch] : 0.0f;
        }

    __syncthreads();
    // C (+bias) -> LDS bf16 [256][CS_LD]
#pragma unroll
    for (int mi = 0; mi < 4; mi++)
#pragma unroll
        for (int ni = 0; ni < 4; ni++)
#pragma unroll
            for (int reg = 0; reg < 4; reg++) {
                const int ch = wid * 64 + mi * 16 + g * 4 + reg;
                const int cell = ni * 16 + l15;
                Csb[ch * CS_LD + cell] = bf16rne(acc[mi][ni][reg] + bv[mi * 4 + reg]);
            }
    __syncthreads();

    // ---- loss epilogue (round-1 verified math; C now bf16 w/ bias folded) ----
    float part[5] = {0.f, 0.f, 0.f, 0.f, 0.f};
    if (t < 192) {
        const int a = t >> 6;
        const int c = t & 63;
        const int cg = cell0 + c;
        if (cg < NCELL) {
            const int hh = cg / FDIM;
            const int ww = cg - hh * FDIM;
            const int chb = a * NCH;
            float v0 = bf16f(Csb[(chb + 0) * CS_LD + c]);
            float v1 = bf16f(Csb[(chb + 1) * CS_LD + c]);
            float v2 = bf16f(Csb[(chb + 2) * CS_LD + c]);
            float v3 = bf16f(Csb[(chb + 3) * CS_LD + c]);
            float v4 = bf16f(Csb[(chb + 4) * CS_LD + c]);
            const float manw[3] = {1.25f, 2.0f, 4.125f};
            const float manh[3] = {1.625f, 3.75f, 2.875f};
            float s0 = sigm(v0), s1 = sigm(v1), s4 = sigm(v4);
            float pw = expf(v2) * manw[a];
            float ph = expf(v3) * manh[a];
            float px = s0 + (float)ww, py = s1 + (float)hh;
            float parea = pw * ph;
            float ptlx = px - 0.5f * pw, ptly = py - 0.5f * ph;
            float pbrx = px + 0.5f * pw, pbry = py + 0.5f * ph;

            float maxiou = -1e30f;
            int aidx = -1;
            for (int k = 0; k < KLAB; k++) {
                const float* r = &Lb[k * 16];
                float tlx = fmaxf(ptlx, r[0]), tly = fmaxf(ptly, r[1]);
                float brx = fminf(pbrx, r[2]), bry = fminf(pbry, r[3]);
                float inter = ((tlx < brx) && (tly < bry)) ? (brx - tlx) * (bry - tly) : 0.0f;
                float iou = (r[5] != 0.0f) ? inter / (parea + r[4] - inter) : 0.0f;
                maxiou = fmaxf(maxiou, iou);
                if (r[12] != 0.0f && (int)r[13] == a && (int)r[14] == ww && (int)r[15] == hh)
                    aidx = k;             // last match wins
            }

            if (aidx >= 0) {
                const float* r = &Lb[aidx * 16];
                float sc = r[11], sc2 = sc * sc;
                part[0] += sc2 * (bce_full(s0, r[6]) + bce_full(s1, r[7]));
                float dw = v2 - r[8], dh = v3 - r[9];
                float whq = dw * dw + dh * dh;
                part[1] += 0.5f * sc2 * whq;
                part[2] += bce1(s4);
                int ci = (int)r[10];
                float l2 = (s0 - r[6]) * (s0 - r[6]) + (s1 - r[7]) * (s1 - r[7]) +
                           sc2 * whq + (s4 - 1.0f) * (s4 - 1.0f);
                float lcls = 0.0f;
                for (int cc = 0; cc < NCLS; cc++) {
                    float s = sigm(bf16f(Csb[(chb + 5 + cc) * CS_LD + c]));
                    if (cc == ci) { lcls += bce1(s); l2 += (s - 1.0f) * (s - 1.0f); }
                    else          { lcls += bce0(s); l2 += s * s; }
                }
                part[3] += lcls;
                part[4] += l2;
            } else {
                bool objm = !(maxiou > 0.7f);
                if (objm) { part[2] += bce0(s4); part[4] += s4 * s4; }
            }
        }
    }

#pragma unroll
    for (int i = 0; i < 5; i++) {
        float v = part[i];
        for (int off = 32; off > 0; off >>= 1) v += __shfl_down(v, off);
        if ((t & 63) == 0) red[t >> 6][i] = v;
    }
    __syncthreads();
    if (t == 0) {
#pragma unroll
        for (int i = 0; i < 5; i++)
            partials[blk * 8 + i] = red[0][i] + red[1][i] + red[2][i] + red[3][i];
    }
}

// ---- final reduction over per-block partials ----
__global__ __launch_bounds__(256) void yolo_fin(const float* __restrict__ partials,
                                                float* __restrict__ out) {
    __shared__ float red[4][8];
    const int t = threadIdx.x;
    float s[5] = {0.f, 0.f, 0.f, 0.f, 0.f};
    for (int r = t; r < NBLK; r += 256)
#pragma unroll
        for (int i = 0; i < 5; i++) s[i] += partials[r * 8 + i];
#pragma unroll
    for (int i = 0; i < 5; i++) {
        float v = s[i];
        for (int off = 32; off > 0; off >>= 1) v += __shfl_down(v, off);
        if ((t & 63) == 0) red[t >> 6][i] = v;
    }
    __syncthreads();
    if (t == 0) {
        float xy  = red[0][0] + red[1][0] + red[2][0] + red[3][0];
        float wh  = red[0][1] + red[1][1] + red[2][1] + red[3][1];
        float obj = red[0][2] + red[1][2] + red[2][2] + red[3][2];
        float cls = red[0][3] + red[1][3] + red[2][3] + red[3][3];
        float l2  = red[0][4] + red[1][4] + red[2][4] + red[3][4];
        out[0] = xy + wh + obj + cls;
        out[1] = xy; out[2] = wh; out[3] = obj; out[4] = cls; out[5] = l2;
    }
}

extern "C" void kernel_launch(void* const* d_in, const int* in_sizes, int n_in,
                              void* d_out, int out_size, void* d_ws, size_t ws_size,
                              hipStream_t stream) {
    const float* xin    = (const float*)d_in[0];
    const float* labels = (const float*)d_in[1];
    const float* Wm     = (const float*)d_in[2];
    const float* bias   = (const float*)d_in[3];
    float* out = (float*)d_out;

    float* partials = (float*)d_ws;                            // 46592 B
    float* lrec  = (float*)((char*)d_ws + 46592);              // 40960 B
    u16*   Wbf   = (u16*)((char*)d_ws + 46592 + 40960);        // 131072 B

    yolo_wconv<<<256, 256, 0, stream>>>(Wm, Wbf);
    yolo_lab<<<(NB * KLAB + 63) / 64, 64, 0, stream>>>(labels, lrec);
    yolo_mfma<<<NBLK, 256, 0, stream>>>(xin, Wbf, bias, lrec, partials);
    yolo_fin<<<1, 256, 0, stream>>>(partials, out);
}